// Round 3
// baseline (295.585 us; speedup 1.0000x reference)
//
#include <hip/hip_runtime.h>
#include <math.h>

#define Mq 40000
#define Ns 40000
#define Hh 16
#define Cc 128
#define Kk 15

typedef unsigned short ushortT;

static __device__ __forceinline__ unsigned int f2bf(float f) {
    union { float f; unsigned int u; } v; v.f = f;
    return (v.u + 0x7FFFu + ((v.u >> 16) & 1u)) >> 16;   // RNE
}
static __device__ __forceinline__ float bf2f(ushortT u) {
    union { unsigned int u; float f; } v; v.u = ((unsigned int)u) << 16;
    return v.f;
}

// ---------------------------------------------------------------------------
// Kernel 0: s_feats (fp32) -> bf16 copy. 8 elems/thread, fully vectorized.
// ---------------------------------------------------------------------------
__global__ __launch_bounds__(256) void to_bf16(
    const float* __restrict__ in, ushortT* __restrict__ out)
{
    const int i = blockIdx.x * 256 + threadIdx.x;       // 640000 threads, 8 elems each
    const float4 a = ((const float4*)in)[i * 2];
    const float4 b = ((const float4*)in)[i * 2 + 1];
    uint4 o;
    o.x = f2bf(a.x) | (f2bf(a.y) << 16);
    o.y = f2bf(a.z) | (f2bf(a.w) << 16);
    o.z = f2bf(b.x) | (f2bf(b.y) << 16);
    o.w = f2bf(b.z) | (f2bf(b.w) << 16);
    ((uint4*)out)[i] = o;
}

// ---------------------------------------------------------------------------
// Kernel 1: q_feats = s_feats@Wq + bq (fp32 out); k_feats = s_feats@Wk + bk (bf16 out)
// 64 rows/block, 256 threads, thread tile 16 rows x 4 cols over 256 cols (q|k).
// col0 = (tid&63)*4  -> lane-dense b128 wtile reads (conflict-free)
// r0   = (tid>>6)*16 -> wave-uniform ftile reads (broadcast, free)
// ---------------------------------------------------------------------------
__global__ __launch_bounds__(256) void qk_gemm(
    const float* __restrict__ s_feats,
    const float* __restrict__ Wq, const float* __restrict__ bq,
    const float* __restrict__ Wk, const float* __restrict__ bk,
    float* __restrict__ q_feats, ushortT* __restrict__ k_bf16)
{
    __shared__ __align__(16) float ftile[32][68];    // [kk][row], transposed, padded
    __shared__ __align__(16) float wtile[32][256];   // [kk][col (q|k)]
    const int tid  = threadIdx.x;
    const int row0 = blockIdx.x * 64;
    const int col0 = (tid & 63) * 4;                 // 0..252 over [q|k]
    const int r0   = (tid >> 6) * 16;

    float acc[16][4];
    {
        const float* __restrict__ bias = (col0 < 128) ? (bq + col0) : (bk + col0 - 128);
        const float b0 = bias[0], b1 = bias[1], b2_ = bias[2], b3 = bias[3];
        #pragma unroll
        for (int r = 0; r < 16; ++r) {
            acc[r][0] = b0; acc[r][1] = b1; acc[r][2] = b2_; acc[r][3] = b3;
        }
    }

    for (int kc = 0; kc < Cc; kc += 32) {
        __syncthreads();
        {   // ftile: 64 rows x 32 k, float4 coalesced loads, transposed store
            int idx = tid;
            #pragma unroll
            for (int n = 0; n < 2; ++n, idx += 256) {
                const int r = idx >> 3, c4 = (idx & 7) * 4;
                const float4 v = *(const float4*)&s_feats[(row0 + r) * Cc + kc + c4];
                ftile[c4 + 0][r] = v.x; ftile[c4 + 1][r] = v.y;
                ftile[c4 + 2][r] = v.z; ftile[c4 + 3][r] = v.w;
            }
        }
        {   // wtile: 32 k x 256 cols, float4 coalesced
            #pragma unroll
            for (int n = 0; n < 8; ++n) {
                const int idx = n * 256 + tid;
                const int kk = idx >> 6, c4 = (idx & 63) * 4;
                const float* __restrict__ Wsrc = (c4 < 128)
                    ? (Wq + (kc + kk) * Cc + c4)
                    : (Wk + (kc + kk) * Cc + (c4 - 128));
                *(float4*)&wtile[kk][c4] = *(const float4*)Wsrc;
            }
        }
        __syncthreads();
        #pragma unroll 8
        for (int kk = 0; kk < 32; ++kk) {
            const float4 w4 = *(const float4*)&wtile[kk][col0];
            const float4 f0 = *(const float4*)&ftile[kk][r0 + 0];
            const float4 f1 = *(const float4*)&ftile[kk][r0 + 4];
            const float4 f2 = *(const float4*)&ftile[kk][r0 + 8];
            const float4 f3 = *(const float4*)&ftile[kk][r0 + 12];
            const float f[16] = {f0.x, f0.y, f0.z, f0.w, f1.x, f1.y, f1.z, f1.w,
                                 f2.x, f2.y, f2.z, f2.w, f3.x, f3.y, f3.z, f3.w};
            #pragma unroll
            for (int r = 0; r < 16; ++r) {
                acc[r][0] = fmaf(f[r], w4.x, acc[r][0]);
                acc[r][1] = fmaf(f[r], w4.y, acc[r][1]);
                acc[r][2] = fmaf(f[r], w4.z, acc[r][2]);
                acc[r][3] = fmaf(f[r], w4.w, acc[r][3]);
            }
        }
    }

    if (col0 < 128) {
        #pragma unroll
        for (int r = 0; r < 16; ++r) {
            const float4 v = make_float4(acc[r][0], acc[r][1], acc[r][2], acc[r][3]);
            *(float4*)&q_feats[(row0 + r0 + r) * Cc + col0] = v;
        }
    } else {
        const int ck = col0 - 128;
        #pragma unroll
        for (int r = 0; r < 16; ++r) {
            ushort4 p;
            p.x = (ushortT)f2bf(acc[r][0]); p.y = (ushortT)f2bf(acc[r][1]);
            p.z = (ushortT)f2bf(acc[r][2]); p.w = (ushortT)f2bf(acc[r][3]);
            *(ushort4*)&k_bf16[(row0 + r0 + r) * Cc + ck] = p;
        }
    }
}

// ---------------------------------------------------------------------------
// Kernel 2: fused geometry + KPConv weighting + grouped attention + aggregate.
// 256 threads = 2 queries; per query 128 threads own one channel c.
// Gathers are bf16 (half traffic); value terms held in 16 registers.
// ---------------------------------------------------------------------------
__global__ __launch_bounds__(256) void kpt_main(
    const float* __restrict__ q_pts, const float* __restrict__ s_pts,
    const ushortT* __restrict__ s_bf16, const int* __restrict__ nb,
    const float* __restrict__ kpts, const float* __restrict__ wkp,
    const float* __restrict__ alpha_w1, const float* __restrict__ alpha_w2,
    const float* __restrict__ alpha_b2,
    const float* __restrict__ q_feats, const ushortT* __restrict__ k_bf16,
    float* __restrict__ out)
{
    // w1v[cb][4*(j^(cb&7)) + q] = alpha_w1[4*cb+q][j]  (XOR-swizzled, conflict-free)
    __shared__ __align__(16) float w1v[32][64];
    __shared__ float wt[15][128];                 // per-kernel-point weights
    __shared__ float w2s[16][17];
    __shared__ float b2s[16];
    __shared__ float kpl[48];
    __shared__ __align__(16) float a_s[2][16][132];  // leaky(q-k), padded
    __shared__ float t_s[2][16][17];
    __shared__ float sg_s[2][16][17];
    __shared__ int   id_s[2][16];
    __shared__ int   nn_s[2][16];
    __shared__ float in_s[2][16];

    const int tid = threadIdx.x;
    const int qs  = tid >> 7;          // 0/1: which query of the pair
    const int c   = tid & 127;         // channel
    const int m   = blockIdx.x * 2 + qs;

    // ---- stage shared weights ----
    w2s[tid >> 4][tid & 15] = alpha_w2[tid];          // 256 = 16x16
    if (tid < 16) b2s[tid] = alpha_b2[tid];
    if (tid < 45) kpl[tid] = kpts[tid];
    if (tid < 128) {
        const int cb = tid >> 2, q = tid & 3;
        #pragma unroll
        for (int jj = 0; jj < 16; ++jj)
            w1v[cb][4 * (jj ^ (cb & 7)) + q] = alpha_w1[tid * 16 + jj];
    } else {
        const int t2 = tid - 128;
        #pragma unroll
        for (int k = 0; k < Kk; ++k)
            wt[k][t2] = wkp[k * Cc + t2];
    }
    const float qf = q_feats[m * Cc + c];
    __syncthreads();

    // ---- geometry: nearest kernel point + influence (16 lanes per query) ----
    if (c < Hh) {
        const int h  = c;
        const int id = nb[m * Hh + h];
        const float px = s_pts[id*3+0] - q_pts[m*3+0];
        const float py = s_pts[id*3+1] - q_pts[m*3+1];
        const float pz = s_pts[id*3+2] - q_pts[m*3+2];
        float best = 1e30f; int bi = 0;
        #pragma unroll
        for (int k = 0; k < Kk; ++k) {
            const float dx = px - kpl[k*3+0];
            const float dy = py - kpl[k*3+1];
            const float dz = pz - kpl[k*3+2];
            const float d = dx*dx + dy*dy + dz*dz;
            if (d < best) { best = d; bi = k; }
        }
        id_s[qs][h] = id;
        nn_s[qs][h] = bi;
        in_s[qs][h] = fmaxf(0.f, 1.f - sqrtf(best) * 0.5f);   // SIGMA=2
    }
    __syncthreads();

    // ---- fused gathers: a = leaky(q - k); v_h = v * w_kp * infl (registers) ----
    float v_h[16];
    #pragma unroll
    for (int h = 0; h < Hh; ++h) {
        const int id = id_s[qs][h];
        const float kv = bf2f(k_bf16[id * Cc + c]);
        const float x  = qf - kv;
        a_s[qs][h][c]  = fmaxf(x, 0.1f * x);          // LeakyReLU(0.1)
        v_h[h] = bf2f(s_bf16[id * Cc + c]) * (wt[nn_s[qs][h]][c] * in_s[qs][h]);
    }
    __syncthreads();

    // ---- first linear (128->16) + leaky: threads = (h-slot, j) ----
    const int j  = c & 15;
    const int hs = c >> 4;               // 0..7
    #pragma unroll
    for (int b = 0; b < 2; ++b) {
        const int h = b * 8 + hs;
        float av = 0.f;
        #pragma unroll 8
        for (int cb = 0; cb < 32; ++cb) {
            const float4 aa = *(const float4*)&a_s[qs][h][cb * 4];
            const float4 ww = *(const float4*)&w1v[cb][4 * (j ^ (cb & 7))];
            av += aa.x*ww.x + aa.y*ww.y + aa.z*ww.z + aa.w*ww.w;
        }
        av = fmaxf(av, 0.1f * av);
        t_s[qs][h][j] = av;
    }
    __syncthreads();

    // ---- second linear (16->16) + bias + sigmoid ----
    #pragma unroll
    for (int b = 0; b < 2; ++b) {
        const int h = b * 8 + hs;
        float av = b2s[j];
        #pragma unroll
        for (int jp = 0; jp < 16; ++jp)
            av = fmaf(t_s[qs][h][jp], w2s[jp][j], av);
        sg_s[qs][h][j] = 1.f / (1.f + __expf(-av));
    }
    __syncthreads();

    // ---- aggregate: out = sum_h v_h * sigmoid[h][group-channel] ----
    float acc = 0.f;
    #pragma unroll
    for (int h = 0; h < Hh; ++h)
        acc = fmaf(v_h[h], sg_s[qs][h][j], acc);
    out[m * Cc + c] = acc;
}

extern "C" void kernel_launch(void* const* d_in, const int* in_sizes, int n_in,
                              void* d_out, int out_size, void* d_ws, size_t ws_size,
                              hipStream_t stream) {
    const float* q_pts   = (const float*)d_in[0];
    const float* s_pts   = (const float*)d_in[1];
    const float* s_feats = (const float*)d_in[2];
    const int*   nb      = (const int*)d_in[3];
    const float* kpts    = (const float*)d_in[4];
    const float* wkp     = (const float*)d_in[5];
    const float* Wq      = (const float*)d_in[6];
    const float* bq      = (const float*)d_in[7];
    const float* Wk      = (const float*)d_in[8];
    const float* bk      = (const float*)d_in[9];
    const float* w1      = (const float*)d_in[10];
    const float* w2      = (const float*)d_in[11];
    const float* b2      = (const float*)d_in[12];
    float* outp = (float*)d_out;

    float*   q_feats = (float*)d_ws;                                  // 20.48 MB
    ushortT* k_bf16  = (ushortT*)(q_feats + (size_t)Mq * Cc);         // 10.24 MB
    ushortT* s_bf16  = k_bf16 + (size_t)Mq * Cc;                      // 10.24 MB

    to_bf16 <<<Mq * Cc / (256 * 8), 256, 0, stream>>>(s_feats, s_bf16);
    qk_gemm <<<Mq / 64, 256, 0, stream>>>(s_feats, Wq, bq, Wk, bk, q_feats, k_bf16);
    kpt_main<<<Mq / 2, 256, 0, stream>>>(q_pts, s_pts, s_bf16, nb, kpts, wkp,
                                         w1, w2, b2, q_feats, k_bf16, outp);
}

// Round 5
// 174.970 us; speedup vs baseline: 1.6893x; 1.6893x over previous
//
#include <hip/hip_runtime.h>
#include <math.h>

#define Mq 40000
#define Cc 128
#define Hh 16
#define Kk 15

typedef unsigned int uint32;
typedef unsigned short ushortT;
typedef short bf16x8 __attribute__((ext_vector_type(8)));
typedef float f32x4 __attribute__((ext_vector_type(4)));

static __device__ __forceinline__ uint32 f2bf_rne(float f) {
    union { float f; uint32 u; } v; v.f = f;
    return (v.u + 0x7FFFu + ((v.u >> 16) & 1u)) >> 16;
}
static __device__ __forceinline__ float bflo(uint32 u) { return __uint_as_float(u << 16); }
static __device__ __forceinline__ float bfhi(uint32 u) { return __uint_as_float(u & 0xFFFF0000u); }
// pack two f32 -> {lo=cvt(a), hi=cvt(b)} bf16 pair, RNE, 1 instruction
static __device__ __forceinline__ uint32 cvtpk(float a, float b) {
    uint32 r; asm("v_cvt_pk_bf16_f32 %0, %1, %2" : "=v"(r) : "v"(a), "v"(b)); return r;
}

// ---------------------------------------------------------------------------
// prep: (a) s_feats f32 -> s_bf16   (b) wT[n][k] = bf16(concat(Wq,Wk)[k][n])
// ---------------------------------------------------------------------------
__global__ __launch_bounds__(256) void prep(
    const float* __restrict__ s_feats, const float* __restrict__ Wq,
    const float* __restrict__ Wk,
    ushortT* __restrict__ s_bf16, ushortT* __restrict__ wT)
{
    const int b = blockIdx.x, t = threadIdx.x;
    if (b < 2500) {                       // 2500*256*8 = 5.12M elems
        const int i = b * 256 + t;
        const float4 a = ((const float4*)s_feats)[i * 2];
        const float4 c = ((const float4*)s_feats)[i * 2 + 1];
        uint4 o;
        o.x = cvtpk(a.x, a.y); o.y = cvtpk(a.z, a.w);
        o.z = cvtpk(c.x, c.y); o.w = cvtpk(c.z, c.w);
        ((uint4*)s_bf16)[i] = o;
    } else {                              // 16 blocks: 128k x 256n transpose
        const int j = (b - 2500) * 256 + t;     // 0..4095
        const int k = j >> 5;                   // 0..127
        const int n0 = (j & 31) * 8;            // 0..248, no q/k crossing
        const float* __restrict__ src = (n0 < 128) ? (Wq + k * 128 + n0)
                                                   : (Wk + k * 128 + n0 - 128);
        #pragma unroll
        for (int e = 0; e < 8; ++e)
            wT[(n0 + e) * 128 + k] = (ushortT)f2bf_rne(src[e]);
    }
}

// ---------------------------------------------------------------------------
// qk_gemm (MFMA, LDS-free): [q|k]_bf16 = bf16(s_feats @ [Wq|Wk] + [bq|bk])
// 256 thr = 4 waves; wave w: rows rowblk*64+w*16, block cols nblk*64.
// A-frag: lane(row=l&15, k=(l>>4)*8+e) direct from s_bf16 (16B loads).
// B-frag: lane(n=l&15, k=(l>>4)*8+e) from wT (n-major, L2-hot).
// ---------------------------------------------------------------------------
__global__ __launch_bounds__(256) void qk_gemm(
    const ushortT* __restrict__ s_bf16, const ushortT* __restrict__ wT,
    const float* __restrict__ bq, const float* __restrict__ bk,
    ushortT* __restrict__ q_bf16, ushortT* __restrict__ k_bf16)
{
    const int tid = threadIdx.x;
    const int w = tid >> 6, l = tid & 63;
    const int lo = l & 15, hi = l >> 4;
    const int rowblk = blockIdx.x >> 2, nblk = blockIdx.x & 3;  // consecutive blocks share A-rows
    const int r0 = rowblk * 64 + w * 16;
    const int n0 = nblk * 64;

    f32x4 acc[4];
    #pragma unroll
    for (int ns = 0; ns < 4; ++ns) {
        const int n = n0 + ns * 16 + lo;
        const float bv = (n < 128) ? bq[n] : bk[n - 128];
        acc[ns] = (f32x4){bv, bv, bv, bv};
    }
    #pragma unroll
    for (int kt = 0; kt < 4; ++kt) {
        const bf16x8 af = *(const bf16x8*)(s_bf16 + (r0 + lo) * Cc + kt * 32 + hi * 8);
        #pragma unroll
        for (int ns = 0; ns < 4; ++ns) {
            const int n = n0 + ns * 16 + lo;
            const bf16x8 bf = *(const bf16x8*)(wT + n * Cc + kt * 32 + hi * 8);
            acc[ns] = __builtin_amdgcn_mfma_f32_16x16x32_bf16(af, bf, acc[ns], 0, 0, 0);
        }
    }
    ushortT* __restrict__ tbl = (n0 < 128) ? q_bf16 : k_bf16;   // uniform per block
    const int nbase = n0 & 127;
    #pragma unroll
    for (int ns = 0; ns < 4; ++ns) {
        const int col = nbase + ns * 16 + lo;          // D: col = lane&15
        #pragma unroll
        for (int r = 0; r < 4; ++r) {                  // D: row = (lane>>4)*4+r
            const int row = r0 + hi * 4 + r;
            tbl[row * Cc + col] = (ushortT)f2bf_rne(acc[ns][r]);
        }
    }
}

// ---------------------------------------------------------------------------
// kpt_main: 256 thr = 4 waves; wave = 4 queries (sequential).
// Per query: gather k/v rows (lane owns ch 2l,2l+1) -> a=leaky(q-k) into
// XOR-swizzled bf16 LDS -> linear1 = 4 MFMA (16x16x32) -> leaky -> t scratch
// -> linear2 = 1 MFMA (K pad 16->32, zero cols) -> sigmoid*infl -> aggregate.
// ---------------------------------------------------------------------------
__global__ __launch_bounds__(256) void kpt_main(
    const float* __restrict__ q_pts, const float* __restrict__ s_pts,
    const ushortT* __restrict__ s_bf16, const int* __restrict__ nb,
    const float* __restrict__ kpts, const float* __restrict__ wkp,
    const float* __restrict__ w1, const float* __restrict__ w2,
    const float* __restrict__ b2,
    const ushortT* __restrict__ q_bf16, const ushortT* __restrict__ k_bf16,
    float* __restrict__ out)
{
    __shared__ __align__(16) uint32 wt_lds[Kk][64];  // kernel-point weights, bf16 pairs
    __shared__ __align__(16) float  kpl[45];
    __shared__ __align__(16) uint32 a_u[4][1024];    // per-wave 16x128 bf16, swizzled
    __shared__ __align__(16) float  t_scr[4][16][36];// cols 16..31 stay zero (K-pad)
    __shared__ __align__(16) float  sg_scr[4][16][18];  // sigmoid*infl
    __shared__ __align__(16) int    id_l[4][4][16];  // id | (nn<<20)
    __shared__ __align__(16) float  in_l[4][4][16];  // influence

    const int tid = threadIdx.x;
    const int w = tid >> 6, l = tid & 63;
    const int lo = l & 15, hi = l >> 4;

    // ---- stage: wt (packed bf16), kpl, zero t-pad ----
    for (int i = tid; i < Kk * 64; i += 256) {
        const int k = i >> 6, c2 = i & 63;
        const float2 v = *(const float2*)(wkp + k * Cc + c2 * 2);
        wt_lds[k][c2] = cvtpk(v.x, v.y);
    }
    if (tid < 45) kpl[tid] = kpts[tid];
    #pragma unroll
    for (int r = 0; r < 4; ++r) t_scr[w][lo][16 + hi * 4 + r] = 0.f;
    __syncthreads();

    const int mq0 = blockIdx.x * 16 + w * 4;

    // ---- geometry: lane covers (qq=hi, h=lo) => all 4 queries in one pass ----
    {
        const int m = mq0 + hi, h = lo;
        const int id = nb[m * Hh + h];
        const float px = s_pts[id * 3 + 0] - q_pts[m * 3 + 0];
        const float py = s_pts[id * 3 + 1] - q_pts[m * 3 + 1];
        const float pz = s_pts[id * 3 + 2] - q_pts[m * 3 + 2];
        float best = 1e30f; int bi = 0;
        #pragma unroll
        for (int k = 0; k < Kk; ++k) {
            const float dx = px - kpl[k * 3 + 0];
            const float dy = py - kpl[k * 3 + 1];
            const float dz = pz - kpl[k * 3 + 2];
            const float d = dx * dx + dy * dy + dz * dz;
            if (d < best) { best = d; bi = k; }
        }
        id_l[w][hi][h] = id | (bi << 20);
        in_l[w][hi][h] = fmaxf(0.f, 1.f - sqrtf(best) * 0.5f);  // SIGMA=2
    }

    // ---- loop-invariant fragments (amortized over 4 queries) ----
    bf16x8 w1f[4];                           // B-frag: w1[k][j], j=lane&15
    #pragma unroll
    for (int kt = 0; kt < 4; ++kt) {
        float tmp[8];
        #pragma unroll
        for (int e = 0; e < 8; ++e)
            tmp[e] = w1[(kt * 32 + hi * 8 + e) * 16 + lo];
        uint32 u[4] = {cvtpk(tmp[0], tmp[1]), cvtpk(tmp[2], tmp[3]),
                       cvtpk(tmp[4], tmp[5]), cvtpk(tmp[6], tmp[7])};
        w1f[kt] = *(bf16x8*)u;
    }
    bf16x8 w2f;                              // B-frag: w2[jp][j], jp>=16 -> 0
    {
        float tmp[8];
        #pragma unroll
        for (int e = 0; e < 8; ++e) {
            const int k = hi * 8 + e;
            tmp[e] = (k < 16) ? w2[k * 16 + lo] : 0.f;
        }
        uint32 u[4] = {cvtpk(tmp[0], tmp[1]), cvtpk(tmp[2], tmp[3]),
                       cvtpk(tmp[4], tmp[5]), cvtpk(tmp[6], tmp[7])};
        w2f = *(bf16x8*)u;
    }
    const float bias2 = b2[lo];
    __syncthreads();

    for (int qq = 0; qq < 4; ++qq) {
        const int m = mq0 + qq;
        int ids[16];
        #pragma unroll
        for (int h = 0; h < Hh; ++h) ids[h] = id_l[w][qq][h];

        const uint32 qv = *(const uint32*)(q_bf16 + m * Cc + 2 * l);
        const float q0 = bflo(qv), q1 = bfhi(qv);

        // batch-issue all 32 gathers (16 k-rows + 16 v-rows), 4B/lane coalesced
        uint32 kv[16], vv[16];
        #pragma unroll
        for (int h = 0; h < Hh; ++h) {
            const int id = ids[h] & 0xFFFFF;
            kv[h] = *(const uint32*)(k_bf16 + id * Cc + 2 * l);
            vv[h] = *(const uint32*)(s_bf16 + id * Cc + 2 * l);
        }
        // a = leaky(q - k) -> swizzled LDS (write word (h*64+l)^((h&7)<<2))
        #pragma unroll
        for (int h = 0; h < Hh; ++h) {
            float a0 = q0 - bflo(kv[h]); a0 = fmaxf(a0, 0.1f * a0);
            float a1 = q1 - bfhi(kv[h]); a1 = fmaxf(a1, 0.1f * a1);
            a_u[w][(h * 64 + l) ^ ((h & 7) << 2)] = cvtpk(a0, a1);
        }
        __syncthreads();

        // linear1: A-frag row=l&15(h), k=(l>>4)*8+e; banks 4*(hi^row&7) = min-cycles
        f32x4 acc1 = {0.f, 0.f, 0.f, 0.f};
        #pragma unroll
        for (int kt = 0; kt < 4; ++kt) {
            const int boff = (lo * 256 + kt * 64 + hi * 16) ^ ((l & 7) << 4);
            const bf16x8 af = *(const bf16x8*)((const char*)&a_u[w][0] + boff);
            acc1 = __builtin_amdgcn_mfma_f32_16x16x32_bf16(af, w1f[kt], acc1, 0, 0, 0);
        }
        #pragma unroll
        for (int r = 0; r < 4; ++r) {        // D: row=h=(l>>4)*4+r, col=j=l&15
            const float v = acc1[r];
            t_scr[w][hi * 4 + r][lo] = fmaxf(v, 0.1f * v);
        }
        __syncthreads();

        // linear2: A-frag = t rows (lane reads row l&15, cols hi*8..+7; >=16 zeros)
        f32x4 acc2 = {bias2, bias2, bias2, bias2};
        {
            const float4 ta = *(const float4*)&t_scr[w][lo][hi * 8];
            const float4 tb = *(const float4*)&t_scr[w][lo][hi * 8 + 4];
            uint32 u[4] = {cvtpk(ta.x, ta.y), cvtpk(ta.z, ta.w),
                           cvtpk(tb.x, tb.y), cvtpk(tb.z, tb.w)};
            const bf16x8 tf = *(const bf16x8*)u;
            acc2 = __builtin_amdgcn_mfma_f32_16x16x32_bf16(tf, w2f, acc2, 0, 0, 0);
        }
        #pragma unroll
        for (int r = 0; r < 4; ++r) {        // fold influence into stored gate
            const float s = 1.f / (1.f + __expf(-acc2[r]));
            sg_scr[w][hi * 4 + r][lo] = s * in_l[w][qq][hi * 4 + r];
        }
        __syncthreads();

        // aggregate: out[c] = sum_h v*wkp[nn]*infl*sig, lane owns c=2l,2l+1
        float o0 = 0.f, o1 = 0.f;
        #pragma unroll
        for (int h = 0; h < Hh; ++h) {
            const uint32 wp = wt_lds[ids[h] >> 20][l];
            const float2 sp = *(const float2*)&sg_scr[w][h][2 * (l & 7)];
            o0 = fmaf(bflo(vv[h]) * bflo(wp), sp.x, o0);
            o1 = fmaf(bfhi(vv[h]) * bfhi(wp), sp.y, o1);
        }
        *(float2*)(out + m * Cc + 2 * l) = make_float2(o0, o1);
        // next-iter hazards (a_u WAR etc.) are covered by the loop's barriers
    }
}

extern "C" void kernel_launch(void* const* d_in, const int* in_sizes, int n_in,
                              void* d_out, int out_size, void* d_ws, size_t ws_size,
                              hipStream_t stream) {
    const float* q_pts   = (const float*)d_in[0];
    const float* s_pts   = (const float*)d_in[1];
    const float* s_feats = (const float*)d_in[2];
    const int*   nb      = (const int*)d_in[3];
    const float* kpts    = (const float*)d_in[4];
    const float* wkp     = (const float*)d_in[5];
    const float* Wq      = (const float*)d_in[6];
    const float* bq      = (const float*)d_in[7];
    const float* Wk      = (const float*)d_in[8];
    const float* bk      = (const float*)d_in[9];
    const float* w1      = (const float*)d_in[10];
    const float* w2      = (const float*)d_in[11];
    const float* b2      = (const float*)d_in[12];
    float* outp = (float*)d_out;

    ushortT* s_bf16 = (ushortT*)d_ws;                         // 10.24 MB
    ushortT* q_bf16 = s_bf16 + (size_t)Mq * Cc;               // 10.24 MB
    ushortT* k_bf16 = q_bf16 + (size_t)Mq * Cc;               // 10.24 MB
    ushortT* wT     = k_bf16 + (size_t)Mq * Cc;               // 64 KB

    prep    <<<2516, 256, 0, stream>>>(s_feats, Wq, Wk, s_bf16, wT);
    qk_gemm <<<2500, 256, 0, stream>>>(s_bf16, wT, bq, bk, q_bf16, k_bf16);
    kpt_main<<<2500, 256, 0, stream>>>(q_pts, s_pts, s_bf16, nb, kpts, wkp,
                                       w1, w2, b2, q_bf16, k_bf16, outp);
}

// Round 10
// 173.257 us; speedup vs baseline: 1.7060x; 1.0099x over previous
//
#include <hip/hip_runtime.h>
#include <math.h>

#define Mq 40000
#define Cc 128
#define Hh 16
#define Kk 15

typedef unsigned int uint32;
typedef unsigned short ushortT;
typedef short bf16x8 __attribute__((ext_vector_type(8)));
typedef float f32x4 __attribute__((ext_vector_type(4)));

static __device__ __forceinline__ uint32 f2bf_rne(float f) {
    union { float f; uint32 u; } v; v.f = f;
    return (v.u + 0x7FFFu + ((v.u >> 16) & 1u)) >> 16;
}
static __device__ __forceinline__ float bflo(uint32 u) { return __uint_as_float(u << 16); }
static __device__ __forceinline__ float bfhi(uint32 u) { return __uint_as_float(u & 0xFFFF0000u); }
static __device__ __forceinline__ uint32 cvtpk(float a, float b) {
    uint32 r; asm("v_cvt_pk_bf16_f32 %0, %1, %2" : "=v"(r) : "v"(a), "v"(b)); return r;
}
// wave-local LDS fence: all this wave's prior ds ops complete & visible to all
// its lanes; sched_barrier stops the compiler hoisting dependent ops above it.
#define WAVE_FENCE() do { \
    asm volatile("s_waitcnt lgkmcnt(0)" ::: "memory"); \
    __builtin_amdgcn_sched_barrier(0); } while (0)

// ---------------------------------------------------------------------------
// prepW: wT[n][k] = bf16(concat(Wq,Wk)[k][n])   (16 blocks, trivial)
// ---------------------------------------------------------------------------
__global__ __launch_bounds__(256) void prepW(
    const float* __restrict__ Wq, const float* __restrict__ Wk,
    ushortT* __restrict__ wT)
{
    const int j = blockIdx.x * 256 + threadIdx.x;   // 0..4095
    const int k = j >> 5;                           // 0..127
    const int n0 = (j & 31) * 8;                    // 0..248, no q/k crossing
    const float* __restrict__ src = (n0 < 128) ? (Wq + k * 128 + n0)
                                               : (Wk + k * 128 + n0 - 128);
    #pragma unroll
    for (int e = 0; e < 8; ++e)
        wT[(n0 + e) * 128 + k] = (ushortT)f2bf_rne(src[e]);
}

// ---------------------------------------------------------------------------
// qk_gemm (MFMA, LDS-free, fused s_bf16 production):
//   reads s_feats f32 once; emits s_bf16, q_bf16, k_bf16.
// 625 blocks x 256 thr = 4 waves; wave w: rows r0 = b*64+w*16, all 256 cols.
// A-frag lane(row=l&15, k=(l>>4)*8+e) built by cvtpk from f32, also stored
// to s_bf16 (16B, each element exactly once). B-frags from wT (L2-hot).
// ---------------------------------------------------------------------------
__global__ __launch_bounds__(256, 4) void qk_gemm(
    const float* __restrict__ s_feats, const ushortT* __restrict__ wT,
    const float* __restrict__ bq, const float* __restrict__ bk,
    ushortT* __restrict__ s_bf16, ushortT* __restrict__ q_bf16,
    ushortT* __restrict__ k_bf16)
{
    const int tid = threadIdx.x;
    const int w = tid >> 6, l = tid & 63;
    const int lo = l & 15, hi = l >> 4;
    const int r0 = blockIdx.x * 64 + w * 16;

    bf16x8 af[4];
    #pragma unroll
    for (int kt = 0; kt < 4; ++kt) {
        const float* __restrict__ p = s_feats + (size_t)(r0 + lo) * Cc + kt * 32 + hi * 8;
        const float4 x = *(const float4*)p;
        const float4 y = *(const float4*)(p + 4);
        uint32 u[4] = {cvtpk(x.x, x.y), cvtpk(x.z, x.w),
                       cvtpk(y.x, y.y), cvtpk(y.z, y.w)};
        af[kt] = *(bf16x8*)u;
        *(uint4*)(s_bf16 + (size_t)(r0 + lo) * Cc + kt * 32 + hi * 8) = *(uint4*)u;
    }

    #pragma unroll
    for (int ns = 0; ns < 16; ++ns) {
        const int n = ns * 16 + lo;                   // output col over [q|k]
        const float bv = (n < 128) ? bq[n] : bk[n - 128];
        f32x4 acc = (f32x4){bv, bv, bv, bv};
        #pragma unroll
        for (int kt = 0; kt < 4; ++kt) {
            const bf16x8 bf = *(const bf16x8*)(wT + n * Cc + kt * 32 + hi * 8);
            acc = __builtin_amdgcn_mfma_f32_16x16x32_bf16(af[kt], bf, acc, 0, 0, 0);
        }
        ushortT* __restrict__ tbl = (ns < 8) ? q_bf16 : k_bf16;  // uniform (lo<16)
        const int col = n & 127;
        #pragma unroll
        for (int r = 0; r < 4; ++r)                   // D: row=(l>>4)*4+r, col=l&15
            tbl[(size_t)(r0 + hi * 4 + r) * Cc + col] = (ushortT)f2bf_rne(acc[r]);
    }
}

// ---------------------------------------------------------------------------
// kpt_main: 2500 blocks x 4 waves; wave = 4 queries (sequential), ALL LDS
// tiles wave-private -> no __syncthreads in the query loop (WAVE_FENCE only).
// ---------------------------------------------------------------------------
__global__ __launch_bounds__(256, 4) void kpt_main(
    const float* __restrict__ q_pts, const float* __restrict__ s_pts,
    const ushortT* __restrict__ s_bf16, const int* __restrict__ nb,
    const float* __restrict__ kpts, const float* __restrict__ wkp,
    const float* __restrict__ w1, const float* __restrict__ w2,
    const float* __restrict__ b2,
    const ushortT* __restrict__ q_bf16, const ushortT* __restrict__ k_bf16,
    float* __restrict__ out)
{
    __shared__ __align__(16) uint32 wt_lds[Kk][64];   // kp weights, bf16 pairs (cross-wave)
    __shared__ __align__(16) float  kpl[45];
    __shared__ __align__(16) uint32 a_u[4][1024];     // per-wave 16x128 bf16, swizzled
    __shared__ __align__(16) float  t_scr[4][16][20]; // 16 cols + pad (K-pad in regs)
    __shared__ __align__(16) float  sg_scr[4][16][18];// sigmoid*infl
    __shared__ __align__(16) int    id_l[4][4][16];   // id | (nn<<20)
    __shared__ __align__(16) float  in_l[4][4][16];   // influence

    const int tid = threadIdx.x;
    const int w = tid >> 6, l = tid & 63;
    const int lo = l & 15, hi = l >> 4;

    // ---- cross-wave staging (the ONLY __syncthreads) ----
    for (int i = tid; i < Kk * 64; i += 256) {
        const int k = i >> 6, c2 = i & 63;
        const float2 v = *(const float2*)(wkp + k * Cc + c2 * 2);
        wt_lds[k][c2] = cvtpk(v.x, v.y);
    }
    if (tid < 45) kpl[tid] = kpts[tid];
    __syncthreads();

    const int mq0 = blockIdx.x * 16 + w * 4;

    // ---- geometry: lane covers (qq=hi, h=lo) -> 4 queries in one pass ----
    {
        const int m = mq0 + hi, h = lo;
        const int id = nb[m * Hh + h];
        const float px = s_pts[id * 3 + 0] - q_pts[m * 3 + 0];
        const float py = s_pts[id * 3 + 1] - q_pts[m * 3 + 1];
        const float pz = s_pts[id * 3 + 2] - q_pts[m * 3 + 2];
        float best = 1e30f; int bi = 0;
        #pragma unroll
        for (int k = 0; k < Kk; ++k) {
            const float dx = px - kpl[k * 3 + 0];
            const float dy = py - kpl[k * 3 + 1];
            const float dz = pz - kpl[k * 3 + 2];
            const float d = dx * dx + dy * dy + dz * dz;
            if (d < best) { best = d; bi = k; }
        }
        id_l[w][hi][h] = id | (bi << 20);
        in_l[w][hi][h] = fmaxf(0.f, 1.f - sqrtf(best) * 0.5f);  // SIGMA=2
    }

    // ---- loop-invariant fragments ----
    bf16x8 w1f[4];                           // B-frag: w1[k][j], j=lane&15
    #pragma unroll
    for (int kt = 0; kt < 4; ++kt) {
        float tmp[8];
        #pragma unroll
        for (int e = 0; e < 8; ++e)
            tmp[e] = w1[(kt * 32 + hi * 8 + e) * 16 + lo];
        uint32 u[4] = {cvtpk(tmp[0], tmp[1]), cvtpk(tmp[2], tmp[3]),
                       cvtpk(tmp[4], tmp[5]), cvtpk(tmp[6], tmp[7])};
        w1f[kt] = *(bf16x8*)u;
    }
    bf16x8 w2f;                              // B-frag: w2[jp][j], jp>=16 -> 0
    {
        float tmp[8];
        #pragma unroll
        for (int e = 0; e < 8; ++e) {
            const int k = hi * 8 + e;
            tmp[e] = (k < 16) ? w2[k * 16 + lo] : 0.f;
        }
        uint32 u[4] = {cvtpk(tmp[0], tmp[1]), cvtpk(tmp[2], tmp[3]),
                       cvtpk(tmp[4], tmp[5]), cvtpk(tmp[6], tmp[7])};
        w2f = *(bf16x8*)u;
    }
    const float bias2 = b2[lo];
    WAVE_FENCE();                            // geometry id_l/in_l visible wave-wide

    for (int qq = 0; qq < 4; ++qq) {
        const int m = mq0 + qq;
        int ids[16];
        #pragma unroll
        for (int h = 0; h < Hh; ++h) ids[h] = id_l[w][qq][h];

        const uint32 qv = *(const uint32*)(q_bf16 + (size_t)m * Cc + 2 * l);
        const float q0 = bflo(qv), q1 = bfhi(qv);

        // batch-issue all 32 gathers (16 k-rows + 16 v-rows), 4B/lane
        uint32 kv[16], vv[16];
        #pragma unroll
        for (int h = 0; h < Hh; ++h) {
            const int id = ids[h] & 0xFFFFF;
            kv[h] = *(const uint32*)(k_bf16 + (size_t)id * Cc + 2 * l);
            vv[h] = *(const uint32*)(s_bf16 + (size_t)id * Cc + 2 * l);
        }
        // a = leaky(q - k) -> swizzled LDS (word (h*64+l)^((h&7)<<2))
        #pragma unroll
        for (int h = 0; h < Hh; ++h) {
            float a0 = q0 - bflo(kv[h]); a0 = fmaxf(a0, 0.1f * a0);
            float a1 = q1 - bfhi(kv[h]); a1 = fmaxf(a1, 0.1f * a1);
            a_u[w][(h * 64 + l) ^ ((h & 7) << 2)] = cvtpk(a0, a1);
        }
        WAVE_FENCE();

        // linear1: A-frag row=l&15(h), k=(l>>4)*8+e
        f32x4 acc1 = {0.f, 0.f, 0.f, 0.f};
        #pragma unroll
        for (int kt = 0; kt < 4; ++kt) {
            const int boff = (lo * 256 + kt * 64 + hi * 16) ^ ((l & 7) << 4);
            const bf16x8 af = *(const bf16x8*)((const char*)&a_u[w][0] + boff);
            acc1 = __builtin_amdgcn_mfma_f32_16x16x32_bf16(af, w1f[kt], acc1, 0, 0, 0);
        }
        #pragma unroll
        for (int r = 0; r < 4; ++r) {        // D: row=h=(l>>4)*4+r, col=j=l&15
            const float v = acc1[r];
            t_scr[w][hi * 4 + r][lo] = fmaxf(v, 0.1f * v);
        }
        WAVE_FENCE();

        // linear2: A-frag = t rows; k>=16 half is register zeros
        f32x4 acc2 = {bias2, bias2, bias2, bias2};
        {
            uint32 u0 = 0, u1 = 0, u2 = 0, u3 = 0;
            if (hi < 2) {
                const float4 ta = *(const float4*)&t_scr[w][lo][hi * 8];
                const float4 tb = *(const float4*)&t_scr[w][lo][hi * 8 + 4];
                u0 = cvtpk(ta.x, ta.y); u1 = cvtpk(ta.z, ta.w);
                u2 = cvtpk(tb.x, tb.y); u3 = cvtpk(tb.z, tb.w);
            }
            uint32 uu[4] = {u0, u1, u2, u3};
            const bf16x8 tf = *(const bf16x8*)uu;
            acc2 = __builtin_amdgcn_mfma_f32_16x16x32_bf16(tf, w2f, acc2, 0, 0, 0);
        }
        #pragma unroll
        for (int r = 0; r < 4; ++r) {        // fold influence into stored gate
            const float s = 1.f / (1.f + __expf(-acc2[r]));
            sg_scr[w][hi * 4 + r][lo] = s * in_l[w][qq][hi * 4 + r];
        }
        WAVE_FENCE();

        // aggregate: out[c] = sum_h v*wkp[nn]*infl*sig, lane owns c=2l,2l+1
        float o0 = 0.f, o1 = 0.f;
        #pragma unroll
        for (int h = 0; h < Hh; ++h) {
            const uint32 wp = wt_lds[ids[h] >> 20][l];
            const float2 sp = *(const float2*)&sg_scr[w][h][2 * (l & 7)];
            o0 = fmaf(bflo(vv[h]) * bflo(wp), sp.x, o0);
            o1 = fmaf(bfhi(vv[h]) * bfhi(wp), sp.y, o1);
        }
        *(float2*)(out + (size_t)m * Cc + 2 * l) = make_float2(o0, o1);
        // WAR on a_u next iter is same-wave program order + fences
    }
}

extern "C" void kernel_launch(void* const* d_in, const int* in_sizes, int n_in,
                              void* d_out, int out_size, void* d_ws, size_t ws_size,
                              hipStream_t stream) {
    const float* q_pts   = (const float*)d_in[0];
    const float* s_pts   = (const float*)d_in[1];
    const float* s_feats = (const float*)d_in[2];
    const int*   nb      = (const int*)d_in[3];
    const float* kpts    = (const float*)d_in[4];
    const float* wkp     = (const float*)d_in[5];
    const float* Wq      = (const float*)d_in[6];
    const float* bq      = (const float*)d_in[7];
    const float* Wk      = (const float*)d_in[8];
    const float* bk      = (const float*)d_in[9];
    const float* w1      = (const float*)d_in[10];
    const float* w2      = (const float*)d_in[11];
    const float* b2      = (const float*)d_in[12];
    float* outp = (float*)d_out;

    ushortT* s_bf16 = (ushortT*)d_ws;                         // 10.24 MB
    ushortT* q_bf16 = s_bf16 + (size_t)Mq * Cc;               // 10.24 MB
    ushortT* k_bf16 = q_bf16 + (size_t)Mq * Cc;               // 10.24 MB
    ushortT* wT     = k_bf16 + (size_t)Mq * Cc;               // 64 KB

    prepW   <<<16,   256, 0, stream>>>(Wq, Wk, wT);
    qk_gemm <<<625,  256, 0, stream>>>(s_feats, wT, bq, bk, s_bf16, q_bf16, k_bf16);
    kpt_main<<<2500, 256, 0, stream>>>(q_pts, s_pts, s_bf16, nb, kpts, wkp,
                                       w1, w2, b2, q_bf16, k_bf16, outp);
}